// Round 8
// baseline (13.408 us; speedup 1.0000x reference)
//
#include <hip/hip_runtime.h>
#include <math.h>

// SSKernelDiag: out[0,h,l] = 2*Re( sum_n C'[h,n] * A[h,n]^l )
//   A  = exp(al + i*ph),  C' = (C0 + i*C1)*(A-1)/(al + i*ph)
// H=256, N=64, L=4096, CH=1.
//
// Round 8: occupancy probe. LPT 16->8, 2048 blocks, launch_bounds(256,8)
// -> 8 waves/SIMD (was 4). If the ~20%-issue-efficiency floor was latency
// (TRANS/LDS/FMA-chain bubbles), 2x TLP should halve dur; if unchanged,
// we're issue-bound -> next step is explicit v_pk_fma_f32.
//   - n split across 4 waves (8 pairs each); same 512-l window per block;
//     cross-wave reduce via conflict-free [j][wave][lane] f32x2 LDS.
//   - T = A^(8*lane) JIT per pair via HW exp/sin/cos (revolutions).
//   - Re-only 2nd-order recurrence r_{j+1} = 2Ar*r_j - |A|^2*r_{j-1}.
//   - phase A: single f64 reduction (ph -> phrev); lbase angle in f32 from
//     phrev (phrev*3584 keeps ~1e-4 rev accuracy, validated by R5-R7).

typedef float f32x2 __attribute__((ext_vector_type(2)));

constexpr int H = 256;
constexpr int N = 64;
constexpr int L = 4096;

constexpr int BLK   = 256;
constexpr int WAVES = 4;
constexpr int NPW   = N / WAVES;     // 16 n per wave
constexpr int PPW   = NPW / 2;       // 8 pairs per wave
constexpr int LPT   = 8;             // l per lane (recurrence chain length)
constexpr int LBLK  = 64 * LPT;      // 512 l per block
constexpr int SPLIT = L / LBLK;      // 8 blocks per head
constexpr int NP    = N / 2;         // 32 pairs

__global__ __launch_bounds__(BLK, 8)
void sskdiag_kernel(const float* __restrict__ A_abslog,
                    const float* __restrict__ A_phase,
                    const float* __restrict__ C,
                    float* __restrict__ out)
{
    __shared__ float4 s_P[NP];     // {Pr0,Pr1,-Pi0,-Pi1},  P = C'*A^lbase
    __shared__ float4 s_Q[NP];     // {Qr0,Qr1,-Qi0,-Qi1},  Q = P*A
    __shared__ float4 s_CC[NP];    // {c1_0,c1_1,c2_0,c2_1}; c1=2Ar, c2=-|A|^2
    __shared__ float4 s_alph[NP];  // {al0,al1,phrev0,phrev1}
    __shared__ f32x2  s_red[LPT][WAVES][64];  // contiguous rows: conflict-free

    const int h     = blockIdx.x >> 3;
    const int lbase = (blockIdx.x & 7) * LBLK;
    const int tid   = threadIdx.x;
    const int w     = tid >> 6;
    const int lane  = tid & 63;

    // ---- phase A: per-n scalars (lanes 0..63) ----
    if (tid < N) {
        const int   n  = tid;
        const float al = A_abslog[h * N + n];
        const float ph = A_phase [h * N + n];
        const double md = (double)ph * 0.15915494309189535;  // /(2*pi)
        const float phrev = (float)(md - floor(md));         // frac revolutions
        const float sp = __builtin_amdgcn_sinf(phrev);       // HW trig: revs
        const float cp = __builtin_amdgcn_cosf(phrev);
        const float m  = __expf(al);
        const float Ar = m * cp, Ai = m * sp;
        const float nr = Ar - 1.0f, ni = Ai;
        const float inv = 1.0f / (al * al + ph * ph);
        const float gr = (nr * al + ni * ph) * inv;
        const float gi = (ni * al - nr * ph) * inv;
        const float cre = C[(h * N + n) * 2 + 0];
        const float cim = C[(h * N + n) * 2 + 1];
        const float Cr = cre * gr - cim * gi;
        const float Ci = cre * gi + cim * gr;
        // P = C' * A^lbase ; lbase angle from already-reduced phrev (f32 ok)
        const float lbf  = (float)lbase;
        const float magP = __expf(al * lbf);
        float tl = phrev * lbf;  tl -= floorf(tl);
        const float er = magP * __builtin_amdgcn_cosf(tl);
        const float ei = magP * __builtin_amdgcn_sinf(tl);
        const float Pr = Cr * er - Ci * ei;
        const float Pi = Cr * ei + Ci * er;
        const float Qr = Pr * Ar - Pi * Ai;
        const float Qi = Pr * Ai + Pi * Ar;
        const int pr = n >> 1, sl = n & 1;
        ((float*)&s_P [pr])[sl]     = Pr;
        ((float*)&s_P [pr])[2 + sl] = -Pi;
        ((float*)&s_Q [pr])[sl]     = Qr;
        ((float*)&s_Q [pr])[2 + sl] = -Qi;
        ((float*)&s_CC[pr])[sl]     = Ar + Ar;
        ((float*)&s_CC[pr])[2 + sl] = -(Ar * Ar + Ai * Ai);
        ((float*)&s_alph[pr])[sl]     = al;
        ((float*)&s_alph[pr])[2 + sl] = phrev;
    }
    __syncthreads();

    // ---- main loop: JIT T + 4 broadcast b128 + packed chain per pair ----
    const float kf = (float)(LPT * lane);

    f32x2 acc[LPT];
    #pragma unroll
    for (int j = 0; j < LPT; ++j) acc[j] = (f32x2){0.f, 0.f};

    #pragma unroll 2
    for (int p = 0; p < PPW; ++p) {
        const float4 ap = s_alph[PPW * w + p];     // broadcast
        const float m0 = __expf(ap.x * kf);
        const float m1 = __expf(ap.y * kf);
        float t0 = ap.z * kf; t0 -= floorf(t0);
        float t1 = ap.w * kf; t1 -= floorf(t1);
        const f32x2 TX = { m0 * __builtin_amdgcn_cosf(t0),
                           m1 * __builtin_amdgcn_cosf(t1) };
        const f32x2 TY = { m0 * __builtin_amdgcn_sinf(t0),
                           m1 * __builtin_amdgcn_sinf(t1) };

        const float4 P  = s_P [PPW * w + p];
        const float4 Q  = s_Q [PPW * w + p];
        const float4 CV = s_CC[PPW * w + p];
        const f32x2 PR = {P.x, P.y},  PI = {P.z, P.w};
        const f32x2 QR = {Q.x, Q.y},  QI = {Q.z, Q.w};
        const f32x2 C1 = {CV.x, CV.y}, C2 = {CV.z, CV.w};

        f32x2 rp = TX * PR + TY * PI;   // Re(T*P)
        f32x2 rc = TX * QR + TY * QI;   // Re(T*P*A)
        acc[0] += rp;
        acc[1] += rc;
        #pragma unroll
        for (int j = 2; j < LPT; ++j) {
            const f32x2 rn = C1 * rc + C2 * rp;
            acc[j] += rn;
            rp = rc; rc = rn;
        }
    }

    // ---- per-wave partials -> LDS ([j][w][lane] rows: b64 conflict-free) ----
    #pragma unroll
    for (int j = 0; j < LPT; ++j)
        s_red[j][w][lane] = acc[j];
    __syncthreads();

    // ---- cross-wave reduce + store: thread t owns 2 consecutive l ----
    {
        const int lp = tid >> 2;          // source lane
        const int jb = (tid & 3) * 2;     // source j base
        f32x2 u0 = {0.f, 0.f}, u1 = {0.f, 0.f};
        #pragma unroll
        for (int ww = 0; ww < WAVES; ++ww) {
            u0 += s_red[jb + 0][ww][lp];
            u1 += s_red[jb + 1][ww][lp];
        }
        float2 v;
        v.x = 2.0f * (u0.x + u0.y);
        v.y = 2.0f * (u1.x + u1.y);
        *reinterpret_cast<float2*>(out + h * L + lbase + lp * LPT + jb) = v;
    }
}

extern "C" void kernel_launch(void* const* d_in, const int* in_sizes, int n_in,
                              void* d_out, int out_size, void* d_ws, size_t ws_size,
                              hipStream_t stream)
{
    const float* A_abslog = (const float*)d_in[0];
    const float* A_phase  = (const float*)d_in[1];
    const float* C        = (const float*)d_in[2];
    float* out = (float*)d_out;

    sskdiag_kernel<<<H * SPLIT, BLK, 0, stream>>>(A_abslog, A_phase, C, out);
}

// Round 9
// 11.424 us; speedup vs baseline: 1.1737x; 1.1737x over previous
//
#include <hip/hip_runtime.h>
#include <math.h>

// SSKernelDiag: out[0,h,l] = 2*Re( sum_n C'[h,n] * A[h,n]^l )
//   A  = exp(al + i*ph),  C' = (C0 + i*C1)*(A-1)/(al + i*ph)
// H=256, N=64, L=4096, CH=1.
//
// Round 9: MFMA restructure. l = 64a + b (a,b in [0,64)) =>
//   K[a,b] = sum_n M[n,a] * G[n,b],  M[n,a] = 2*C'_n*U_n^a (U=A^64),
//   G[n,b] = A_n^b.  Re(K) = Mr^T Gr - Mi^T Gi -> per head one 64x64x64
//   real-pair matmul = 64 x mfma_f32_16x16x32_f16 (K=64 in 2 steps).
// One wave per head (grid 256 x 64). Fragments are computed DIRECTLY in
// MFMA lane positions: lane needs n = 32s + (lane>>4)*8 + j, and its
// b = a = lane&15; tile offsets (tb,ta in [0,4)) advance by precomputed
// A^16 / A^1024 complex multiplies, so only tile-0 needs transcendentals.
// Output: D[row=b][col=a], row=(lane>>4)*4+reg, col=lane&15 (m89-verified
// layout) -> 4 consecutive l per acc quad -> float4 stores.

typedef _Float16 f16x8 __attribute__((ext_vector_type(8)));
typedef float    f32x4 __attribute__((ext_vector_type(4)));

constexpr int H = 256;
constexpr int N = 64;
constexpr int L = 4096;

__global__ void sskdiag_kernel(const float* __restrict__ A_abslog,
                               const float* __restrict__ A_phase,
                               const float* __restrict__ C,
                               float* __restrict__ out)
{
    __shared__ float4 s_tabA[N];  // {al, phrev, 2C'r, 2C'i}
    __shared__ float4 s_tabB[N];  // {W16r, W16i, U16r, U16i}  (A^16, A^1024)

    const int h    = blockIdx.x;
    const int lane = threadIdx.x;          // 0..63, one wave per block

    // ---- phase A: lane n computes per-n constants ----
    {
        const int n = lane;
        const float al = A_abslog[h * N + n];
        const float ph = A_phase [h * N + n];
        const double md = (double)ph * 0.15915494309189535;   // ph/(2*pi)
        const float phrev = (float)(md - floor(md));          // frac revolutions
        const float sp = __builtin_amdgcn_sinf(phrev);        // HW trig: revs
        const float cp = __builtin_amdgcn_cosf(phrev);
        const float m  = __expf(al);
        const float Ar = m * cp, Ai = m * sp;
        const float nr = Ar - 1.0f, ni = Ai;
        const float inv = 1.0f / (al * al + ph * ph);
        const float gr = (nr * al + ni * ph) * inv;
        const float gi = (ni * al - nr * ph) * inv;
        const float cre = C[(h * N + n) * 2 + 0];
        const float cim = C[(h * N + n) * 2 + 1];
        const float Cr = 2.0f * (cre * gr - cim * gi);        // fold the *2
        const float Ci = 2.0f * (cre * gi + cim * gr);
        // W16 = A^16, U16 = A^1024; angles from f64 md (exact reduction)
        const double m16 = 16.0 * md, m1024 = 1024.0 * md;
        const float f16a  = (float)(m16   - floor(m16));
        const float f1024 = (float)(m1024 - floor(m1024));
        const float mg16   = __expf(16.0f * al);
        const float mg1024 = __expf(1024.0f * al);
        s_tabA[n] = make_float4(al, phrev, Cr, Ci);
        s_tabB[n] = make_float4(mg16   * __builtin_amdgcn_cosf(f16a),
                                mg16   * __builtin_amdgcn_sinf(f16a),
                                mg1024 * __builtin_amdgcn_cosf(f1024),
                                mg1024 * __builtin_amdgcn_sinf(f1024));
    }
    __syncthreads();   // single wave: just orders LDS writes vs reads

    const int e  = lane & 15;              // b (G) and a (M) offset in tile 0
    const int kg = lane >> 4;              // k-group (which 8 n's this lane holds)

    // frags: [s][tile];  fGi holds NEGATED Gi so Re = mfma(Gr,Mr)+mfma(-Gi,Mi)
    f16x8 fGr[2][4], fGi[2][4], fMr[2][4], fMi[2][4];

    #pragma unroll
    for (int s = 0; s < 2; ++s) {
        #pragma unroll
        for (int j = 0; j < 8; ++j) {
            const int n = 32 * s + 8 * kg + j;
            const float4 tA = s_tabA[n];
            const float4 tB = s_tabB[n];
            // G tile 0: A_n^b at b=e
            float tg = tA.y * (float)e;  tg -= floorf(tg);
            const float magg = __expf(tA.x * (float)e);
            float gr_ = magg * __builtin_amdgcn_cosf(tg);
            float gi_ = magg * __builtin_amdgcn_sinf(tg);
            // M tile 0: 2C'_n * A_n^(64a) at a=e
            float tm = tA.y * (float)(64 * e);  tm -= floorf(tm);
            const float magm = __expf(tA.x * (float)(64 * e));
            const float ur = magm * __builtin_amdgcn_cosf(tm);
            const float ui = magm * __builtin_amdgcn_sinf(tm);
            float mr_ = tA.z * ur - tA.w * ui;
            float mi_ = tA.z * ui + tA.w * ur;
            // walk tiles: G *= A^16, M *= A^1024
            #pragma unroll
            for (int tt = 0; tt < 4; ++tt) {
                fGr[s][tt][j] = (_Float16)gr_;
                fGi[s][tt][j] = (_Float16)(-gi_);
                fMr[s][tt][j] = (_Float16)mr_;
                fMi[s][tt][j] = (_Float16)mi_;
                if (tt < 3) {
                    const float ngr = gr_ * tB.x - gi_ * tB.y;
                    gi_ = gr_ * tB.y + gi_ * tB.x;  gr_ = ngr;
                    const float nmr = mr_ * tB.z - mi_ * tB.w;
                    mi_ = mr_ * tB.w + mi_ * tB.z;  mr_ = nmr;
                }
            }
        }
    }

    // ---- 16 output tiles, 4 mfma each (2 K-steps x {Re,Im} terms) ----
    #pragma unroll
    for (int ta = 0; ta < 4; ++ta) {
        #pragma unroll
        for (int tb = 0; tb < 4; ++tb) {
            f32x4 acc = {0.f, 0.f, 0.f, 0.f};
            #pragma unroll
            for (int s = 0; s < 2; ++s) {
                acc = __builtin_amdgcn_mfma_f32_16x16x32_f16(fGr[s][tb], fMr[s][ta], acc, 0, 0, 0);
                acc = __builtin_amdgcn_mfma_f32_16x16x32_f16(fGi[s][tb], fMi[s][ta], acc, 0, 0, 0);
            }
            // D[row=b][col=a]: b = tb*16 + kg*4 + reg, a = ta*16 + e
            const int a  = ta * 16 + e;
            float4 v;
            v.x = acc[0];  v.y = acc[1];  v.z = acc[2];  v.w = acc[3];
            *reinterpret_cast<float4*>(out + h * L + a * 64 + tb * 16 + kg * 4) = v;
        }
    }
}

extern "C" void kernel_launch(void* const* d_in, const int* in_sizes, int n_in,
                              void* d_out, int out_size, void* d_ws, size_t ws_size,
                              hipStream_t stream)
{
    const float* A_abslog = (const float*)d_in[0];
    const float* A_phase  = (const float*)d_in[1];
    const float* C        = (const float*)d_in[2];
    float* out = (float*)d_out;

    sskdiag_kernel<<<H, 64, 0, stream>>>(A_abslog, A_phase, C, out);
}

// Round 10
// 9.782 us; speedup vs baseline: 1.3706x; 1.1678x over previous
//
#include <hip/hip_runtime.h>
#include <math.h>

// SSKernelDiag: out[0,h,l] = 2*Re( sum_n C'[h,n] * A[h,n]^l )
//   A  = exp(al + i*ph),  C' = (C0 + i*C1)*(A-1)/(al + i*ph)
// H=256, N=64, L=4096, CH=1.
//
// Round 10: MFMA + table-parallel setup (decisive overhead probe).
//   l = 64a + b;  K[a,b] = sum_n M[n,a]*G[n,b], M = 2C'*U^a (U=A^64), G = A^b.
//   Re(K) = Gr^T Mr - Gi^T Mi  ->  mfma_f32_16x16x32_f16.
// One head per 256-thread block (grid=256). Thread (n=tid&63, q=tid>>6)
// seeds G/M at row 16q with 6 HW transcendentals, walks 16 rows by complex
// mul, writes packed {f16 r, f16 -i} u32 entries (stride-1 across lanes:
// conflict-free). Waves then read MFMA-ready b128 fragments from padded
// rows (STRIDE=76 words) and each computes 4 output tiles (ta = wave id).
// Per-thread transcendentals: 96 (R9) -> 6.

typedef _Float16 f16x8 __attribute__((ext_vector_type(8)));
typedef unsigned short u16x8 __attribute__((ext_vector_type(8)));
typedef unsigned int   u32x4 __attribute__((ext_vector_type(4)));
typedef float          f32x4 __attribute__((ext_vector_type(4)));

constexpr int H = 256;
constexpr int N = 64;
constexpr int L = 4096;
constexpr int STRIDE = 76;   // u32 words per table row (64 + 12 pad, 16B-mult)

__global__ __launch_bounds__(256)
void sskdiag_kernel(const float* __restrict__ A_abslog,
                    const float* __restrict__ A_phase,
                    const float* __restrict__ C,
                    float* __restrict__ out)
{
    __shared__ float4   s_t1[N];            // {al, phrev, Ar, Ai}
    __shared__ float4   s_t2[N];            // {Ur, Ui, 2C'r, 2C'i}
    __shared__ unsigned s_G[64 * STRIDE];   // row b: packed {f16 Gr, f16 -Gi}
    __shared__ unsigned s_M[64 * STRIDE];   // row a: packed {f16 Mr, f16  Mi}

    const int h   = blockIdx.x;
    const int tid = threadIdx.x;

    // ---- phase A: lane n computes per-n constants (one wave) ----
    if (tid < N) {
        const int n = tid;
        const float al = A_abslog[h * N + n];
        const float ph = A_phase [h * N + n];
        const double md = (double)ph * 0.15915494309189535;   // ph/(2*pi)
        const float phrev = (float)(md - floor(md));          // frac revolutions
        const float sp = __builtin_amdgcn_sinf(phrev);        // HW trig: revs
        const float cp = __builtin_amdgcn_cosf(phrev);
        const float m  = __expf(al);
        const float Ar = m * cp, Ai = m * sp;
        const float nr = Ar - 1.0f, ni = Ai;
        const float inv = 1.0f / (al * al + ph * ph);
        const float gr = (nr * al + ni * ph) * inv;
        const float gi = (ni * al - nr * ph) * inv;
        const float cre = C[(h * N + n) * 2 + 0];
        const float cim = C[(h * N + n) * 2 + 1];
        const float Cr = 2.0f * (cre * gr - cim * gi);        // fold the *2
        const float Ci = 2.0f * (cre * gi + cim * gr);
        // U = A^64 (angle from f64 md: exact reduction)
        const double m64 = 64.0 * md;
        const float f64a = (float)(m64 - floor(m64));
        const float mg64 = __expf(64.0f * al);
        s_t1[n] = make_float4(al, phrev, Ar, Ai);
        s_t2[n] = make_float4(mg64 * __builtin_amdgcn_cosf(f64a),
                              mg64 * __builtin_amdgcn_sinf(f64a), Cr, Ci);
    }
    __syncthreads();

    // ---- table fill: thread (n, q) seeds row 16q, walks 16 rows ----
    {
        const int n = tid & 63, q = tid >> 6;
        const float4 t1 = s_t1[n];
        const float4 t2 = s_t2[n];
        const float al = t1.x, phrev = t1.y;
        const float Ar = t1.z, Ai = t1.w;
        const float Ur = t2.x, Ui = t2.y;
        // G seed: A^(16q)
        const float b0 = (float)(16 * q);
        float tg = phrev * b0;  tg -= floorf(tg);
        const float gmag = __expf(al * b0);
        float gre = gmag * __builtin_amdgcn_cosf(tg);
        float gim = gmag * __builtin_amdgcn_sinf(tg);
        // M seed: 2C' * U^(16q)   (exponent 1024q on A)
        const float a64 = (float)(1024 * q);
        float tm = phrev * a64;  tm -= floorf(tm);
        const float umag = __expf(al * a64);
        const float ure = umag * __builtin_amdgcn_cosf(tm);
        const float uim = umag * __builtin_amdgcn_sinf(tm);
        float mre = t2.z * ure - t2.w * uim;
        float mim = t2.z * uim + t2.w * ure;

        #pragma unroll
        for (int k = 0; k < 16; ++k) {
            const int row = 16 * q + k;
            union { _Float16 hh[2]; unsigned u; } pg, pm;
            pg.hh[0] = (_Float16)gre;  pg.hh[1] = (_Float16)(-gim);  // -Gi
            pm.hh[0] = (_Float16)mre;  pm.hh[1] = (_Float16)mim;
            s_G[row * STRIDE + n] = pg.u;   // lanes n: stride-1, conflict-free
            s_M[row * STRIDE + n] = pm.u;
            const float ngr = gre * Ar - gim * Ai;              // g *= A
            gim = gre * Ai + gim * Ar;  gre = ngr;
            const float nmr = mre * Ur - mim * Ui;              // m *= U
            mim = mre * Ui + mim * Ur;  mre = nmr;
        }
    }
    __syncthreads();

    // ---- fragment read (b128) + unpack; wave w owns ta = w ----
    const int w    = tid >> 6;
    const int lane = tid & 63;
    const int e    = lane & 15;
    const int kg   = lane >> 4;

    f16x8 fGr[2][4], fGi[2][4], fMr[2], fMi[2];

    #pragma unroll
    for (int s = 0; s < 2; ++s) {
        #pragma unroll
        for (int tb = 0; tb < 4; ++tb) {
            const unsigned* p = &s_G[(tb * 16 + e) * STRIDE + 32 * s + 8 * kg];
            const u32x4 v0 = *reinterpret_cast<const u32x4*>(p);
            const u32x4 v1 = *reinterpret_cast<const u32x4*>(p + 4);
            u16x8 rr, ii;
            #pragma unroll
            for (int k = 0; k < 4; ++k) {
                rr[k]     = (unsigned short)(v0[k] & 0xffffu);
                ii[k]     = (unsigned short)(v0[k] >> 16);
                rr[k + 4] = (unsigned short)(v1[k] & 0xffffu);
                ii[k + 4] = (unsigned short)(v1[k] >> 16);
            }
            fGr[s][tb] = __builtin_bit_cast(f16x8, rr);
            fGi[s][tb] = __builtin_bit_cast(f16x8, ii);
        }
        {
            const unsigned* p = &s_M[(w * 16 + e) * STRIDE + 32 * s + 8 * kg];
            const u32x4 v0 = *reinterpret_cast<const u32x4*>(p);
            const u32x4 v1 = *reinterpret_cast<const u32x4*>(p + 4);
            u16x8 rr, ii;
            #pragma unroll
            for (int k = 0; k < 4; ++k) {
                rr[k]     = (unsigned short)(v0[k] & 0xffffu);
                ii[k]     = (unsigned short)(v0[k] >> 16);
                rr[k + 4] = (unsigned short)(v1[k] & 0xffffu);
                ii[k + 4] = (unsigned short)(v1[k] >> 16);
            }
            fMr[s] = __builtin_bit_cast(f16x8, rr);
            fMi[s] = __builtin_bit_cast(f16x8, ii);
        }
    }

    // ---- 4 output tiles per wave: Re = mfma(Gr,Mr) + mfma(-Gi,Mi) ----
    #pragma unroll
    for (int tb = 0; tb < 4; ++tb) {
        f32x4 acc = {0.f, 0.f, 0.f, 0.f};
        #pragma unroll
        for (int s = 0; s < 2; ++s) {
            acc = __builtin_amdgcn_mfma_f32_16x16x32_f16(fGr[s][tb], fMr[s], acc, 0, 0, 0);
            acc = __builtin_amdgcn_mfma_f32_16x16x32_f16(fGi[s][tb], fMi[s], acc, 0, 0, 0);
        }
        // D[row=b][col=a]: b = tb*16 + kg*4 + reg, a = w*16 + e
        const int a = w * 16 + e;
        float4 v;
        v.x = acc[0];  v.y = acc[1];  v.z = acc[2];  v.w = acc[3];
        *reinterpret_cast<float4*>(out + h * L + a * 64 + tb * 16 + kg * 4) = v;
    }
}

extern "C" void kernel_launch(void* const* d_in, const int* in_sizes, int n_in,
                              void* d_out, int out_size, void* d_ws, size_t ws_size,
                              hipStream_t stream)
{
    const float* A_abslog = (const float*)d_in[0];
    const float* A_phase  = (const float*)d_in[1];
    const float* C        = (const float*)d_in[2];
    float* out = (float*)d_out;

    sskdiag_kernel<<<H, 256, 0, stream>>>(A_abslog, A_phase, C, out);
}